// Round 2
// baseline (377.236 us; speedup 1.0000x reference)
//
#include <hip/hip_runtime.h>
#include <hip/hip_bf16.h>
#include <cstdint>
#include <cstddef>

typedef _Float16 f16;
typedef _Float16 f16x8 __attribute__((ext_vector_type(8)));
typedef float f32x4 __attribute__((ext_vector_type(4)));

// Problem constants
#define BATCH 16
#define INC   128
#define OUTC  128
#define HH    64
#define WW    64
#define HP    66   // padded
#define WP    66
#define ZDIM  256

// Workspace layout (f16 elements)
#define XP_ELEMS (16ull * HP * WP * INC)            // 8,921,088 f16
#define WA_ELEMS (16ull * 9 * OUTC * INC)           // 2,359,296 f16

// ---------------------------------------------------------------------------
// Kernel 1: zero the padded-x buffer (borders stay zero; interior overwritten)
// ---------------------------------------------------------------------------
__global__ __launch_bounds__(256) void zero_xp(f16* __restrict__ xp) {
    size_t i = (size_t)blockIdx.x * 256 + threadIdx.x;   // one uint4 (8 f16) each
    uint4 zv = {0u, 0u, 0u, 0u};
    *(uint4*)(xp + i * 8) = zv;
}

// ---------------------------------------------------------------------------
// Kernel 2: x [B][IC][H][W] fp32  ->  xp [B][HP][WP][IC] f16 (NHWC, padded)
// block = (b, h, ic-chunk of 32); LDS-staged transpose
// ---------------------------------------------------------------------------
__global__ __launch_bounds__(256) void xprep(const float* __restrict__ x,
                                             f16* __restrict__ xp) {
    int blk = blockIdx.x;
    int icC = blk & 3;            // 4 chunks of 32 ic
    int h   = (blk >> 2) & 63;
    int b   = blk >> 8;
    int ic0 = icC * 32;
    int tid = threadIdx.x;

    __shared__ float tile[32 * 65];   // [ic][w], pad 65 to break bank stride

    // load: 32 ic-rows x 64 w floats, coalesced along w
    {
        int i = tid >> 3;         // ic 0..31
        int j = tid & 7;          // 8-float chunk
        const float4* src = (const float4*)(x + (((size_t)b * INC + ic0 + i) * HH + h) * WW) + j * 2;
        float4 v0 = src[0];
        float4 v1 = src[1];
        float* tp = tile + i * 65 + j * 8;
        tp[0] = v0.x; tp[1] = v0.y; tp[2] = v0.z; tp[3] = v0.w;
        tp[4] = v1.x; tp[5] = v1.y; tp[6] = v1.z; tp[7] = v1.w;
    }
    __syncthreads();
    // store: per w, 32 contiguous ic as f16 (4 threads x 16B)
    {
        int w = tid >> 2;         // 0..63
        int q = tid & 3;          // which 8-ic group
        f16 o8[8];
#pragma unroll
        for (int jj = 0; jj < 8; ++jj)
            o8[jj] = (f16)tile[(q * 8 + jj) * 65 + w];
        f16* dst = xp + (((size_t)b * HP + (h + 1)) * WP + (w + 1)) * INC + ic0 + q * 8;
        *(uint4*)dst = *(uint4*)o8;
    }
}

// ---------------------------------------------------------------------------
// Kernel 3: per-sample weights — COALESCED LDS-staged version
// wA[b][r][oc][ic] f16 = base[oc][ic][kh][kw] + head_b[o] + dot(z[b], head_w[o])
// o = (oc*128+ic)*9 + r,  r = kh*3+kw
// Block of 256 threads owns 256 consecutive rows o. k tiled at 32 floats:
//   stage head_w[256 rows x 32 k] coalesced into LDS (pitch 36 -> even bank
//   spread on both write and read), then thread t FMAs its own row vs z
//   (z indices lane-uniform -> scalar loads).
// ---------------------------------------------------------------------------
__global__ __launch_bounds__(256) void wgen(const float* __restrict__ z,
                                            const float* __restrict__ base_w,
                                            const float* __restrict__ head_w,
                                            const float* __restrict__ head_b,
                                            f16* __restrict__ wA) {
    int tid = threadIdx.x;
    int o0  = blockIdx.x * 256;
    int o   = o0 + tid;

    // 256 rows x 32 floats, pitch 36 floats:
    //  write: lane(r=idx>>3,p=idx&7) -> dword bank ((r+p)&7)*4+d : 8 dwords/bank, even
    //  read:  lane t, part p -> bank ((t+p)&7)*4+d : even           -> conflict-free
    __shared__ float hw_tile[256 * 36];   // 36 KB

    const float4* z4  = (const float4*)z;
    const float4* hw4 = (const float4*)head_w;

    float acc[16];
#pragma unroll
    for (int b = 0; b < 16; ++b) acc[b] = 0.f;

    for (int kt = 0; kt < 8; ++kt) {
        __syncthreads();   // previous iter's LDS reads done
#pragma unroll
        for (int i = 0; i < 8; ++i) {
            int idx  = tid + i * 256;     // 0..2047
            int row  = idx >> 3;
            int part = idx & 7;
            float4 v = hw4[(size_t)(o0 + row) * 64 + kt * 8 + part];
            *(float4*)(hw_tile + row * 36 + part * 4) = v;
        }
        __syncthreads();
#pragma unroll
        for (int part = 0; part < 8; ++part) {
            float4 hv = *(const float4*)(hw_tile + tid * 36 + part * 4);
#pragma unroll
            for (int b = 0; b < 16; ++b) {
                float4 zb = z4[b * 64 + kt * 8 + part];   // lane-uniform -> s_load
                acc[b] = fmaf(hv.x, zb.x, acc[b]);
                acc[b] = fmaf(hv.y, zb.y, acc[b]);
                acc[b] = fmaf(hv.z, zb.z, acc[b]);
                acc[b] = fmaf(hv.w, zb.w, acc[b]);
            }
        }
    }

    float cst = base_w[o] + head_b[o];
    int r  = o % 9;
    int oc = o / 1152;                 // /(128*9)
    int ic = (o / 9) % 128;
    size_t outbase = ((size_t)r * OUTC + oc) * INC + ic;
#pragma unroll
    for (int b = 0; b < 16; ++b)
        wA[(size_t)b * (9 * OUTC * INC) + outbase] = (f16)(cst + acc[b]);
}

// ---------------------------------------------------------------------------
// Kernel 4: conv as implicit GEMM, f16 MFMA 16x16x32  (unchanged from R0)
// block: 256 thr (4 waves), computes 128 oc x 128 pixels (2 output rows)
// wave (ocHalf,pHalf): 64 oc x 64 pix = 4x4 MFMA tiles -> 0.5 ds_read/MFMA
// K-loop: ic-chunks of 32 (4) x kh (3) staged, kw (3) via LDS shift
// ---------------------------------------------------------------------------
__global__ __launch_bounds__(256) void conv(const f16* __restrict__ xp,
                                            const f16* __restrict__ wA,
                                            float* __restrict__ out) {
    int blk = blockIdx.x;         // 512 = 16 b * 32 row-pairs
    int b  = blk >> 5;
    int pt = blk & 31;
    int h0 = pt * 2;              // output rows h0, h0+1

    int tid   = threadIdx.x;
    int lane  = tid & 63;
    int wv    = tid >> 6;
    int ocHalf = wv & 1;
    int pHalf  = wv >> 1;
    int m0    = ocHalf * 64;
    int row16 = lane & 15;
    int quad  = lane >> 4;

    // pitch 40 f16 (80 B = 20 words) -> 2-way bank aliasing only (free)
    __shared__ __align__(16) f16 ws3[3 * 128 * 40];  // [kw][oc][ic32]
    __shared__ __align__(16) f16 xs[2 * 66 * 40];    // [row][wcol][ic32]

    f32x4 acc[4][4];
#pragma unroll
    for (int mt = 0; mt < 4; ++mt)
#pragma unroll
        for (int nt = 0; nt < 4; ++nt)
            acc[mt][nt] = f32x4{0.f, 0.f, 0.f, 0.f};

    for (int c = 0; c < 4; ++c) {
        int ic0 = c * 32;
#pragma unroll
        for (int kh = 0; kh < 3; ++kh) {
            __syncthreads();
            // stage weights: r = kh*3+kw, oc 0..127, 32 ic -> 1536 x 16B
#pragma unroll
            for (int i = 0; i < 6; ++i) {
                int idx  = tid + i * 256;
                int seg  = idx >> 2;          // 0..383
                int part = idx & 3;
                int kw = seg >> 7;            // 0..2
                int oc = seg & 127;
                const uint4* src = (const uint4*)(wA +
                    ((((size_t)b * 9 + kh * 3 + kw) * OUTC + oc) * INC + ic0)) + part;
                *(uint4*)(ws3 + (kw * 128 + oc) * 40 + part * 8) = *src;
            }
            // stage x: rows h0+kh, h0+kh+1; 66 wcols x 32 ic -> 528 x 16B
            for (int idx = tid; idx < 528; idx += 256) {
                int seg  = idx >> 2;          // 0..131
                int part = idx & 3;
                int row  = seg / 66;
                int wc   = seg - row * 66;
                const uint4* src = (const uint4*)(xp +
                    (((size_t)b * HP + h0 + kh + row) * WP + wc) * INC + ic0) + part;
                *(uint4*)(xs + (row * 66 + wc) * 40 + part * 8) = *src;
            }
            __syncthreads();
#pragma unroll
            for (int kw = 0; kw < 3; ++kw) {
                f16x8 afr[4], bfr[4];
#pragma unroll
                for (int mt = 0; mt < 4; ++mt)
                    afr[mt] = *(const f16x8*)(ws3 + ((kw * 128 + m0 + mt * 16 + row16) * 40 + quad * 8));
#pragma unroll
                for (int nt = 0; nt < 4; ++nt)
                    bfr[nt] = *(const f16x8*)(xs + ((pHalf * 66 + nt * 16 + row16 + kw) * 40 + quad * 8));
#pragma unroll
                for (int mt = 0; mt < 4; ++mt)
#pragma unroll
                    for (int nt = 0; nt < 4; ++nt)
                        acc[mt][nt] = __builtin_amdgcn_mfma_f32_16x16x32_f16(
                            afr[mt], bfr[nt], acc[mt][nt], 0, 0, 0);
            }
        }
    }

    // epilogue: D row = oc (quad*4+reg), col = pixel-in-row (lane&15)
    int hrow = h0 + pHalf;
#pragma unroll
    for (int mt = 0; mt < 4; ++mt)
#pragma unroll
        for (int nt = 0; nt < 4; ++nt) {
            int wc = nt * 16 + row16;
#pragma unroll
            for (int reg = 0; reg < 4; ++reg) {
                int oc = m0 + mt * 16 + quad * 4 + reg;
                out[(((size_t)b * OUTC + oc) * HH + hrow) * WW + wc] = acc[mt][nt][reg];
            }
        }
}

// ---------------------------------------------------------------------------
extern "C" void kernel_launch(void* const* d_in, const int* in_sizes, int n_in,
                              void* d_out, int out_size, void* d_ws, size_t ws_size,
                              hipStream_t stream) {
    const float* x      = (const float*)d_in[0];
    const float* z      = (const float*)d_in[1];
    const float* base_w = (const float*)d_in[2];
    const float* head_w = (const float*)d_in[3];
    const float* head_b = (const float*)d_in[4];
    float* out = (float*)d_out;

    f16* xp = (f16*)d_ws;               // XP_ELEMS f16
    f16* wAp = xp + XP_ELEMS;           // WA_ELEMS f16 (offset 16B-aligned)

    zero_xp<<<(unsigned)(XP_ELEMS / 8 / 256), 256, 0, stream>>>(xp);        // 4356 blocks
    xprep  <<<16 * 64 * 4, 256, 0, stream>>>(x, xp);                        // 4096 blocks
    wgen   <<<(OUTC * INC * 9) / 256, 256, 0, stream>>>(z, base_w, head_w,  // 576 blocks
                                                        head_b, wAp);
    conv   <<<16 * 32, 256, 0, stream>>>(xp, wAp, out);                     // 512 blocks
}

// Round 3
// 302.084 us; speedup vs baseline: 1.2488x; 1.2488x over previous
//
#include <hip/hip_runtime.h>
#include <hip/hip_bf16.h>
#include <cstdint>
#include <cstddef>

typedef _Float16 f16;
typedef _Float16 f16x8 __attribute__((ext_vector_type(8)));
typedef float f32x4 __attribute__((ext_vector_type(4)));

// Problem constants
#define BATCH 16
#define INC   128
#define OUTC  128
#define HH    64
#define WW    64
#define HP    66   // padded
#define WP    66
#define ZDIM  256

// Workspace layout (f16 elements)
#define XP_ELEMS (16ull * HP * WP * INC)            // 8,921,088 f16
#define WA_ELEMS (16ull * 9 * OUTC * INC)           // 2,359,296 f16

// ---------------------------------------------------------------------------
// Kernel 1: zero the padded-x buffer (borders stay zero; interior overwritten)
// ---------------------------------------------------------------------------
__global__ __launch_bounds__(256) void zero_xp(f16* __restrict__ xp) {
    size_t i = (size_t)blockIdx.x * 256 + threadIdx.x;   // one uint4 (8 f16) each
    uint4 zv = {0u, 0u, 0u, 0u};
    *(uint4*)(xp + i * 8) = zv;
}

// ---------------------------------------------------------------------------
// Kernel 2: x [B][IC][H][W] fp32  ->  xp [B][HP][WP][IC] f16 (NHWC, padded)
// block = (b, h, ic-chunk of 32); LDS-staged transpose
// ---------------------------------------------------------------------------
__global__ __launch_bounds__(256) void xprep(const float* __restrict__ x,
                                             f16* __restrict__ xp) {
    int blk = blockIdx.x;
    int icC = blk & 3;            // 4 chunks of 32 ic
    int h   = (blk >> 2) & 63;
    int b   = blk >> 8;
    int ic0 = icC * 32;
    int tid = threadIdx.x;

    __shared__ float tile[32 * 65];   // [ic][w], pad 65 to break bank stride

    // load: 32 ic-rows x 64 w floats, coalesced along w
    {
        int i = tid >> 3;         // ic 0..31
        int j = tid & 7;          // 8-float chunk
        const float4* src = (const float4*)(x + (((size_t)b * INC + ic0 + i) * HH + h) * WW) + j * 2;
        float4 v0 = src[0];
        float4 v1 = src[1];
        float* tp = tile + i * 65 + j * 8;
        tp[0] = v0.x; tp[1] = v0.y; tp[2] = v0.z; tp[3] = v0.w;
        tp[4] = v1.x; tp[5] = v1.y; tp[6] = v1.z; tp[7] = v1.w;
    }
    __syncthreads();
    // store: per w, 32 contiguous ic as f16 (4 threads x 16B)
    {
        int w = tid >> 2;         // 0..63
        int q = tid & 3;          // which 8-ic group
        f16 o8[8];
#pragma unroll
        for (int jj = 0; jj < 8; ++jj)
            o8[jj] = (f16)tile[(q * 8 + jj) * 65 + w];
        f16* dst = xp + (((size_t)b * HP + (h + 1)) * WP + (w + 1)) * INC + ic0 + q * 8;
        *(uint4*)dst = *(uint4*)o8;
    }
}

// ---------------------------------------------------------------------------
// Kernel 3: per-sample weights — streaming MFMA GEMM, no LDS, no barriers
// Computes delta[o][b] = dot(head_w[o,:], z[b,:]) via mfma_f32_16x16x32_f16:
//   per wave: 16 rows (M) x 16 batches (N), K=256 in 8 unrolled steps.
//   A[m=lane&15][k=quad*8+j] = head_w row fragment (2 x dwordx4 + cvt)
//   B[k=quad*8+j][n=lane&15] = z[n][k]  -> loaded ONCE, register-resident
//   D[m=quad*4+reg][n=lane&15]
// wA[b][r][oc][ic] f16 = base[oc][ic][kh][kw] + head_b[o] + delta[o][b],
//   o = (oc*128+ic)*9 + r
// Grid: 147456 rows / (4 waves x 16 rows) = 2304 blocks.
// ---------------------------------------------------------------------------
__device__ inline f16x8 cvt8(float4 a, float4 b) {
    f16x8 r;
    r[0] = (f16)a.x; r[1] = (f16)a.y; r[2] = (f16)a.z; r[3] = (f16)a.w;
    r[4] = (f16)b.x; r[5] = (f16)b.y; r[6] = (f16)b.z; r[7] = (f16)b.w;
    return r;
}

__global__ __launch_bounds__(256) void wgen(const float* __restrict__ z,
                                            const float* __restrict__ base_w,
                                            const float* __restrict__ head_w,
                                            const float* __restrict__ head_b,
                                            f16* __restrict__ wA) {
    int tid  = threadIdx.x;
    int lane = tid & 63;
    int wv   = tid >> 6;
    int r16  = lane & 15;
    int quad = lane >> 4;
    int row0 = (blockIdx.x * 4 + wv) * 16;    // first of this wave's 16 rows
    int myrow = row0 + r16;

    // B fragments: z[batch=r16][k], k = s*32 + quad*8 + j. 16 KB total, L2-hot.
    const float4* zrow = (const float4*)(z + (size_t)r16 * ZDIM);
    f16x8 bfr[8];
#pragma unroll
    for (int s = 0; s < 8; ++s) {
        float4 z0 = zrow[s * 8 + quad * 2];
        float4 z1 = zrow[s * 8 + quad * 2 + 1];
        bfr[s] = cvt8(z0, z1);
    }

    // A stream: head_w row myrow; 16 independent dwordx4 loads, full unroll.
    const float4* hw = (const float4*)(head_w + (size_t)myrow * ZDIM);
    f32x4 acc = {0.f, 0.f, 0.f, 0.f};
#pragma unroll
    for (int s = 0; s < 8; ++s) {
        float4 a0 = hw[s * 8 + quad * 2];
        float4 a1 = hw[s * 8 + quad * 2 + 1];
        acc = __builtin_amdgcn_mfma_f32_16x16x32_f16(cvt8(a0, a1), bfr[s], acc, 0, 0, 0);
    }

    // epilogue: lane holds D[m=quad*4+reg][n=r16]; o = row0+m, batch = r16
#pragma unroll
    for (int reg = 0; reg < 4; ++reg) {
        int o = row0 + quad * 4 + reg;
        float cst = base_w[o] + head_b[o];      // broadcast across the 16 n-lanes
        int r  = o % 9;
        int oc = o / 1152;                      // /(128*9)
        int ic = (o / 9) % 128;
        wA[(size_t)r16 * (9 * OUTC * INC) + ((size_t)r * OUTC + oc) * INC + ic] =
            (f16)(cst + acc[reg]);
    }
}

// ---------------------------------------------------------------------------
// Kernel 4: conv as implicit GEMM, f16 MFMA 16x16x32  (unchanged)
// block: 256 thr (4 waves), computes 128 oc x 128 pixels (2 output rows)
// wave (ocHalf,pHalf): 64 oc x 64 pix = 4x4 MFMA tiles -> 0.5 ds_read/MFMA
// K-loop: ic-chunks of 32 (4) x kh (3) staged, kw (3) via LDS shift
// ---------------------------------------------------------------------------
__global__ __launch_bounds__(256) void conv(const f16* __restrict__ xp,
                                            const f16* __restrict__ wA,
                                            float* __restrict__ out) {
    int blk = blockIdx.x;         // 512 = 16 b * 32 row-pairs
    int b  = blk >> 5;
    int pt = blk & 31;
    int h0 = pt * 2;              // output rows h0, h0+1

    int tid   = threadIdx.x;
    int lane  = tid & 63;
    int wv    = tid >> 6;
    int ocHalf = wv & 1;
    int pHalf  = wv >> 1;
    int m0    = ocHalf * 64;
    int row16 = lane & 15;
    int quad  = lane >> 4;

    // pitch 40 f16 (80 B = 20 words) -> 2-way bank aliasing only (free)
    __shared__ __align__(16) f16 ws3[3 * 128 * 40];  // [kw][oc][ic32]
    __shared__ __align__(16) f16 xs[2 * 66 * 40];    // [row][wcol][ic32]

    f32x4 acc[4][4];
#pragma unroll
    for (int mt = 0; mt < 4; ++mt)
#pragma unroll
        for (int nt = 0; nt < 4; ++nt)
            acc[mt][nt] = f32x4{0.f, 0.f, 0.f, 0.f};

    for (int c = 0; c < 4; ++c) {
        int ic0 = c * 32;
#pragma unroll
        for (int kh = 0; kh < 3; ++kh) {
            __syncthreads();
            // stage weights: r = kh*3+kw, oc 0..127, 32 ic -> 1536 x 16B
#pragma unroll
            for (int i = 0; i < 6; ++i) {
                int idx  = tid + i * 256;
                int seg  = idx >> 2;          // 0..383
                int part = idx & 3;
                int kw = seg >> 7;            // 0..2
                int oc = seg & 127;
                const uint4* src = (const uint4*)(wA +
                    ((((size_t)b * 9 + kh * 3 + kw) * OUTC + oc) * INC + ic0)) + part;
                *(uint4*)(ws3 + (kw * 128 + oc) * 40 + part * 8) = *src;
            }
            // stage x: rows h0+kh, h0+kh+1; 66 wcols x 32 ic -> 528 x 16B
            for (int idx = tid; idx < 528; idx += 256) {
                int seg  = idx >> 2;          // 0..131
                int part = idx & 3;
                int row  = seg / 66;
                int wc   = seg - row * 66;
                const uint4* src = (const uint4*)(xp +
                    (((size_t)b * HP + h0 + kh + row) * WP + wc) * INC + ic0) + part;
                *(uint4*)(xs + (row * 66 + wc) * 40 + part * 8) = *src;
            }
            __syncthreads();
#pragma unroll
            for (int kw = 0; kw < 3; ++kw) {
                f16x8 afr[4], bfr[4];
#pragma unroll
                for (int mt = 0; mt < 4; ++mt)
                    afr[mt] = *(const f16x8*)(ws3 + ((kw * 128 + m0 + mt * 16 + row16) * 40 + quad * 8));
#pragma unroll
                for (int nt = 0; nt < 4; ++nt)
                    bfr[nt] = *(const f16x8*)(xs + ((pHalf * 66 + nt * 16 + row16 + kw) * 40 + quad * 8));
#pragma unroll
                for (int mt = 0; mt < 4; ++mt)
#pragma unroll
                    for (int nt = 0; nt < 4; ++nt)
                        acc[mt][nt] = __builtin_amdgcn_mfma_f32_16x16x32_f16(
                            afr[mt], bfr[nt], acc[mt][nt], 0, 0, 0);
            }
        }
    }

    // epilogue: D row = oc (quad*4+reg), col = pixel-in-row (lane&15)
    int hrow = h0 + pHalf;
#pragma unroll
    for (int mt = 0; mt < 4; ++mt)
#pragma unroll
        for (int nt = 0; nt < 4; ++nt) {
            int wc = nt * 16 + row16;
#pragma unroll
            for (int reg = 0; reg < 4; ++reg) {
                int oc = m0 + mt * 16 + quad * 4 + reg;
                out[(((size_t)b * OUTC + oc) * HH + hrow) * WW + wc] = acc[mt][nt][reg];
            }
        }
}

// ---------------------------------------------------------------------------
extern "C" void kernel_launch(void* const* d_in, const int* in_sizes, int n_in,
                              void* d_out, int out_size, void* d_ws, size_t ws_size,
                              hipStream_t stream) {
    const float* x      = (const float*)d_in[0];
    const float* z      = (const float*)d_in[1];
    const float* base_w = (const float*)d_in[2];
    const float* head_w = (const float*)d_in[3];
    const float* head_b = (const float*)d_in[4];
    float* out = (float*)d_out;

    f16* xp = (f16*)d_ws;               // XP_ELEMS f16
    f16* wAp = xp + XP_ELEMS;           // WA_ELEMS f16 (offset 16B-aligned)

    zero_xp<<<(unsigned)(XP_ELEMS / 8 / 256), 256, 0, stream>>>(xp);        // 4356 blocks
    xprep  <<<16 * 64 * 4, 256, 0, stream>>>(x, xp);                        // 4096 blocks
    wgen   <<<(OUTC * INC * 9) / 64, 256, 0, stream>>>(z, base_w, head_w,   // 2304 blocks
                                                       head_b, wAp);
    conv   <<<16 * 32, 256, 0, stream>>>(xp, wAp, out);                     // 512 blocks
}

// Round 4
// 288.741 us; speedup vs baseline: 1.3065x; 1.0462x over previous
//
#include <hip/hip_runtime.h>
#include <hip/hip_bf16.h>
#include <cstdint>
#include <cstddef>

typedef _Float16 f16;
typedef _Float16 f16x8 __attribute__((ext_vector_type(8)));
typedef _Float16 f16x4 __attribute__((ext_vector_type(4)));
typedef float f32x4 __attribute__((ext_vector_type(4)));

// Problem constants
#define BATCH 16
#define INC   128
#define OUTC  128
#define HH    64
#define WW    64
#define HP    66   // padded
#define WP    66
#define ZDIM  256

// Workspace layout (f16 elements)
#define XP_ELEMS (16ull * HP * WP * INC)            // 8,921,088 f16
#define WA_ELEMS (16ull * 9 * OUTC * INC)           // 2,359,296 f16

// ---------------------------------------------------------------------------
// Kernel 1: zero ONLY the border cells of xp (interior is fully overwritten
// by xprep). Border per b: rows 0 & 65 (66 wc each) + cols 0 & 65 of rows
// 1..64 -> 33280 f16 = 4160 uint4 per b, 66560 uint4 total = 260 blocks.
// ---------------------------------------------------------------------------
__global__ __launch_bounds__(256) void zero_xp(f16* __restrict__ xp) {
    unsigned i = blockIdx.x * 256 + threadIdx.x;   // one uint4 (8 f16)
    unsigned b = i / 4160;
    unsigned j = i - b * 4160;
    unsigned row, wc, ic8;
    if (j < 2112) {                 // rows 0 and 65, full width
        row = (j < 1056) ? 0u : 65u;
        unsigned jj = (j < 1056) ? j : j - 1056;
        wc  = jj >> 4;              // 0..65
        ic8 = jj & 15;
    } else {                        // rows 1..64, cols 0 and 65
        unsigned j2 = j - 2112;
        row = 1 + (j2 >> 5);        // 32 chunks per row
        unsigned k = j2 & 31;
        wc  = (k < 16) ? 0u : 65u;
        ic8 = k & 15;
    }
    uint4 zv = {0u, 0u, 0u, 0u};
    *(uint4*)(xp + (((size_t)b * HP + row) * WP + wc) * INC + ic8 * 8) = zv;
}

// ---------------------------------------------------------------------------
// Kernel 2: x [B][IC][H][W] fp32  ->  xp [B][HP][WP][IC] f16 (NHWC, padded)
// block = (b, h, ic-chunk of 32); LDS-staged transpose
// ---------------------------------------------------------------------------
__global__ __launch_bounds__(256) void xprep(const float* __restrict__ x,
                                             f16* __restrict__ xp) {
    int blk = blockIdx.x;
    int icC = blk & 3;            // 4 chunks of 32 ic
    int h   = (blk >> 2) & 63;
    int b   = blk >> 8;
    int ic0 = icC * 32;
    int tid = threadIdx.x;

    __shared__ float tile[32 * 65];   // [ic][w], pad 65 to break bank stride

    {
        int i = tid >> 3;         // ic 0..31
        int j = tid & 7;          // 8-float chunk
        const float4* src = (const float4*)(x + (((size_t)b * INC + ic0 + i) * HH + h) * WW) + j * 2;
        float4 v0 = src[0];
        float4 v1 = src[1];
        float* tp = tile + i * 65 + j * 8;
        tp[0] = v0.x; tp[1] = v0.y; tp[2] = v0.z; tp[3] = v0.w;
        tp[4] = v1.x; tp[5] = v1.y; tp[6] = v1.z; tp[7] = v1.w;
    }
    __syncthreads();
    {
        int w = tid >> 2;         // 0..63
        int q = tid & 3;          // which 8-ic group
        f16 o8[8];
#pragma unroll
        for (int jj = 0; jj < 8; ++jj)
            o8[jj] = (f16)tile[(q * 8 + jj) * 65 + w];
        f16* dst = xp + (((size_t)b * HP + (h + 1)) * WP + (w + 1)) * INC + ic0 + q * 8;
        *(uint4*)dst = *(uint4*)o8;
    }
}

// ---------------------------------------------------------------------------
// Kernel 3: per-sample weights — streaming MFMA GEMM, ic-major tiling.
// Wave tile: 16 GEMM rows = 16 consecutive ic at fixed (oc,r)  (o stride 9),
// 16 cols = batches. D[m=quad*4+reg][n=r16] -> lane's 4 accs are 4
// consecutive ic -> ONE 8B store per thread (vs 64-line 2B scatter before).
// A-loads: rolling prefetch depth 2 (4 loads in flight, ~110 VGPR).
// ---------------------------------------------------------------------------
__device__ inline f16x8 cvt8(float4 a, float4 b) {
    f16x8 r;
    r[0] = (f16)a.x; r[1] = (f16)a.y; r[2] = (f16)a.z; r[3] = (f16)a.w;
    r[4] = (f16)b.x; r[5] = (f16)b.y; r[6] = (f16)b.z; r[7] = (f16)b.w;
    return r;
}

__global__ __launch_bounds__(256) void wgen(const float* __restrict__ z,
                                            const float* __restrict__ base_w,
                                            const float* __restrict__ head_w,
                                            const float* __restrict__ head_b,
                                            f16* __restrict__ wA) {
    int tid  = threadIdx.x;
    int lane = tid & 63;
    int wv   = tid >> 6;
    int r16  = lane & 15;
    int quad = lane >> 4;
    int tile = blockIdx.x * 4 + wv;          // 0..9215
    int icb  = tile & 7;                     // ic block of 16
    int oc   = (tile >> 3) & 127;
    int r    = tile >> 10;                   // 0..8
    int base = (oc * 128 + icb * 16) * 9 + r;
    int myrow = base + 9 * r16;              // this lane's A row (m = r16)

    // B fragments: z[batch=r16][k], loaded once, register-resident
    const float4* zrow = (const float4*)(z + (size_t)r16 * ZDIM);
    f16x8 bfr[8];
#pragma unroll
    for (int s = 0; s < 8; ++s)
        bfr[s] = cvt8(zrow[s * 8 + quad * 2], zrow[s * 8 + quad * 2 + 1]);

    // A stream with rolling prefetch (depth 2)
    const float4* hw = (const float4*)(head_w + (size_t)myrow * ZDIM);
    float4 a[3][2];
    a[0][0] = hw[quad * 2];     a[0][1] = hw[quad * 2 + 1];
    a[1][0] = hw[8 + quad * 2]; a[1][1] = hw[8 + quad * 2 + 1];
    f32x4 acc = {0.f, 0.f, 0.f, 0.f};
#pragma unroll
    for (int s = 0; s < 8; ++s) {
        if (s + 2 < 8) {
            a[(s + 2) % 3][0] = hw[(s + 2) * 8 + quad * 2];
            a[(s + 2) % 3][1] = hw[(s + 2) * 8 + quad * 2 + 1];
        }
        acc = __builtin_amdgcn_mfma_f32_16x16x32_f16(
            cvt8(a[s % 3][0], a[s % 3][1]), bfr[s], acc, 0, 0, 0);
    }

    // epilogue: b = r16 (n), ic_local = quad*4+reg (m); one 8B store
    f16x4 ov;
    int icl = quad * 4;
#pragma unroll
    for (int reg = 0; reg < 4; ++reg) {
        int o = base + 9 * (icl + reg);
        ov[reg] = (f16)(base_w[o] + head_b[o] + acc[reg]);
    }
    size_t idx = (((size_t)r16 * 9 + r) * OUTC + oc) * INC + icb * 16 + icl;
    *(f16x4*)(wA + idx) = ov;
}

// ---------------------------------------------------------------------------
// Kernel 4: conv as implicit GEMM, f16 MFMA 16x16x32.
// Change vs R3: x rows h0..h0+3 staged ONCE per ic-chunk (xs[4][66][40])
// instead of 2 rows re-staged per kh (3x redundancy removed).
// ---------------------------------------------------------------------------
__global__ __launch_bounds__(256) void conv(const f16* __restrict__ xp,
                                            const f16* __restrict__ wA,
                                            float* __restrict__ out) {
    int blk = blockIdx.x;         // 512 = 16 b * 32 row-pairs
    int b  = blk >> 5;
    int pt = blk & 31;
    int h0 = pt * 2;              // output rows h0, h0+1

    int tid   = threadIdx.x;
    int lane  = tid & 63;
    int wv    = tid >> 6;
    int ocHalf = wv & 1;
    int pHalf  = wv >> 1;
    int m0    = ocHalf * 64;
    int row16 = lane & 15;
    int quad  = lane >> 4;

    // pitch 40 f16 (20 dwords) -> 2-way bank aliasing only (free)
    __shared__ __align__(16) f16 ws3[3 * 128 * 40];  // [kw][oc][ic32]
    __shared__ __align__(16) f16 xs[4 * 66 * 40];    // [row 0..3][wcol][ic32]

    f32x4 acc[4][4];
#pragma unroll
    for (int mt = 0; mt < 4; ++mt)
#pragma unroll
        for (int nt = 0; nt < 4; ++nt)
            acc[mt][nt] = f32x4{0.f, 0.f, 0.f, 0.f};

    for (int c = 0; c < 4; ++c) {
        int ic0 = c * 32;
#pragma unroll
        for (int kh = 0; kh < 3; ++kh) {
            __syncthreads();
            // stage weights for this (c, kh): 3 kw x 128 oc x 32 ic
#pragma unroll
            for (int i = 0; i < 6; ++i) {
                int idx  = tid + i * 256;
                int seg  = idx >> 2;          // 0..383
                int part = idx & 3;
                int kw = seg >> 7;            // 0..2
                int oc = seg & 127;
                const uint4* src = (const uint4*)(wA +
                    ((((size_t)b * 9 + kh * 3 + kw) * OUTC + oc) * INC + ic0)) + part;
                *(uint4*)(ws3 + (kw * 128 + oc) * 40 + part * 8) = *src;
            }
            // stage x once per c: rows h0..h0+3, 66 wcols x 32 ic
            if (kh == 0) {
                for (int idx = tid; idx < 1056; idx += 256) {
                    int seg  = idx >> 2;          // 0..263
                    int part = idx & 3;
                    int row  = seg / 66;          // 0..3
                    int wc   = seg - row * 66;
                    const uint4* src = (const uint4*)(xp +
                        (((size_t)b * HP + h0 + row) * WP + wc) * INC + ic0) + part;
                    *(uint4*)(xs + (row * 66 + wc) * 40 + part * 8) = *src;
                }
            }
            __syncthreads();
#pragma unroll
            for (int kw = 0; kw < 3; ++kw) {
                f16x8 afr[4], bfr[4];
#pragma unroll
                for (int mt = 0; mt < 4; ++mt)
                    afr[mt] = *(const f16x8*)(ws3 + ((kw * 128 + m0 + mt * 16 + row16) * 40 + quad * 8));
#pragma unroll
                for (int nt = 0; nt < 4; ++nt)
                    bfr[nt] = *(const f16x8*)(xs + (((kh + pHalf) * 66 + nt * 16 + row16 + kw) * 40 + quad * 8));
#pragma unroll
                for (int mt = 0; mt < 4; ++mt)
#pragma unroll
                    for (int nt = 0; nt < 4; ++nt)
                        acc[mt][nt] = __builtin_amdgcn_mfma_f32_16x16x32_f16(
                            afr[mt], bfr[nt], acc[mt][nt], 0, 0, 0);
            }
        }
    }

    // epilogue: D row = oc (quad*4+reg), col = pixel-in-row (lane&15)
    int hrow = h0 + pHalf;
#pragma unroll
    for (int mt = 0; mt < 4; ++mt)
#pragma unroll
        for (int nt = 0; nt < 4; ++nt) {
            int wc = nt * 16 + row16;
#pragma unroll
            for (int reg = 0; reg < 4; ++reg) {
                int oc = m0 + mt * 16 + quad * 4 + reg;
                out[(((size_t)b * OUTC + oc) * HH + hrow) * WW + wc] = acc[mt][nt][reg];
            }
        }
}

// ---------------------------------------------------------------------------
extern "C" void kernel_launch(void* const* d_in, const int* in_sizes, int n_in,
                              void* d_out, int out_size, void* d_ws, size_t ws_size,
                              hipStream_t stream) {
    const float* x      = (const float*)d_in[0];
    const float* z      = (const float*)d_in[1];
    const float* base_w = (const float*)d_in[2];
    const float* head_w = (const float*)d_in[3];
    const float* head_b = (const float*)d_in[4];
    float* out = (float*)d_out;

    f16* xp = (f16*)d_ws;               // XP_ELEMS f16
    f16* wAp = xp + XP_ELEMS;           // WA_ELEMS f16 (offset 16B-aligned)

    zero_xp<<<260, 256, 0, stream>>>(xp);                                   // borders only
    xprep  <<<16 * 64 * 4, 256, 0, stream>>>(x, xp);                        // 4096 blocks
    wgen   <<<(OUTC * INC * 9) / 64, 256, 0, stream>>>(z, base_w, head_w,   // 2304 blocks
                                                       head_b, wAp);
    conv   <<<16 * 32, 256, 0, stream>>>(xp, wAp, out);                     // 512 blocks
}